// Round 4
// baseline (671.965 us; speedup 1.0000x reference)
//
#include <hip/hip_runtime.h>
#include <math.h>

// InfoNCE loss: B=4096 rows, N=127 negatives, D=256, fp32.
// R4: occupancy-oriented restructure. One block per row; 16 groups x 16
// lanes. Group g owns vectors v = g + 16*it (it=0..7; v=0 is the
// positive). Hot loop: outer over 4 chunks of D, inner over 8 vectors —
// 8 loads in flight per cluster, pointers hoisted, low VGPR pressure
// (target ~100 VGPR -> 5 waves/SIMD) to maximize reads-in-flight per CU.
// Reductions (16-lane xor-shuffles) batched at the end, off the load path.

namespace {
constexpr int B = 4096;
constexpr int N = 127;
constexpr int D = 256;
constexpr int V = N + 1;
constexpr float INV_TEMP = 1.0f / 0.07f;
constexpr float EPS = 1e-12f;

typedef float f32x4 __attribute__((ext_vector_type(4)));

__device__ __forceinline__ float group16_reduce_sum(float v) {
    #pragma unroll
    for (int off = 1; off < 16; off <<= 1) v += __shfl_xor(v, off, 64);
    return v;
}
__device__ __forceinline__ float wave_reduce_sum(float v) {
    #pragma unroll
    for (int off = 32; off > 0; off >>= 1) v += __shfl_xor(v, off, 64);
    return v;
}
__device__ __forceinline__ float wave_reduce_max(float v) {
    #pragma unroll
    for (int off = 32; off > 0; off >>= 1) v = fmaxf(v, __shfl_xor(v, off, 64));
    return v;
}
} // namespace

__global__ __launch_bounds__(256) void infonce_rows(
    const float* __restrict__ anchor,
    const float* __restrict__ positive,
    const float* __restrict__ negatives,
    float* __restrict__ row_loss)
{
    const int b   = blockIdx.x;
    const int tid = threadIdx.x;
    const int sub = tid & 15;   // lane within 16-group
    const int g   = tid >> 4;   // 16-group id, 0..15

    __shared__ float scores[V];

    // --- anchor fragment: lane holds elements {i*64 + sub*4 .. +3} ---
    const float* arow = anchor + (size_t)b * D;
    f32x4 aa[4];
    #pragma unroll
    for (int i = 0; i < 4; ++i)
        aa[i] = *reinterpret_cast<const f32x4*>(arow + i * 64 + sub * 4);
    float asq = 0.f;
    #pragma unroll
    for (int i = 0; i < 4; ++i)
        asq += aa[i].x*aa[i].x + aa[i].y*aa[i].y + aa[i].z*aa[i].z + aa[i].w*aa[i].w;
    asq = group16_reduce_sum(asq);
    const float ainv = 1.0f / fmaxf(sqrtf(asq), EPS);
    #pragma unroll
    for (int i = 0; i < 4; ++i) aa[i] *= ainv;

    // --- hoisted per-vector base pointers (8 per group) ---
    const float* pv[8];
    #pragma unroll
    for (int it = 0; it < 8; ++it) {
        const int v = g + 16 * it;
        pv[it] = (v == 0)
            ? (positive + (size_t)b * D)
            : (negatives + ((size_t)b * N + (size_t)(v - 1)) * D);
    }

    // --- streaming: outer chunk i, inner 8 vectors -> 8 loads/cluster ---
    float dot[8] = {0,0,0,0,0,0,0,0};
    float sq[8]  = {0,0,0,0,0,0,0,0};
    #pragma unroll
    for (int i = 0; i < 4; ++i) {
        f32x4 x[8];
        #pragma unroll
        for (int it = 0; it < 8; ++it)
            x[it] = *reinterpret_cast<const f32x4*>(pv[it] + i * 64 + sub * 4);
        const f32x4 a = aa[i];
        #pragma unroll
        for (int it = 0; it < 8; ++it) {
            dot[it] += a.x*x[it].x + a.y*x[it].y + a.z*x[it].z + a.w*x[it].w;
            sq[it]  += x[it].x*x[it].x + x[it].y*x[it].y
                     + x[it].z*x[it].z + x[it].w*x[it].w;
        }
    }

    // --- batched group reductions (off the memory path) ---
    #pragma unroll
    for (int it = 0; it < 8; ++it) {
        const float d = group16_reduce_sum(dot[it]);
        const float s = group16_reduce_sum(sq[it]);
        if (sub == 0)
            scores[g + 16 * it] = d / fmaxf(sqrtf(s), EPS);
    }
    __syncthreads();

    // --- logsumexp over 128 logits (first wave) ---
    if (tid < 64) {
        const int lane = tid;
        const float s0 = scores[lane]      * INV_TEMP;
        const float s1 = scores[lane + 64] * INV_TEMP;
        float m = wave_reduce_max(fmaxf(s0, s1));
        float e = expf(s0 - m) + expf(s1 - m);
        e = wave_reduce_sum(e);
        if (lane == 0)
            row_loss[b] = m + logf(e) - scores[0] * INV_TEMP;
    }
}

__global__ __launch_bounds__(256) void reduce_mean(
    const float* __restrict__ row_loss, float* __restrict__ out)
{
    __shared__ float wsum[4];
    const int tid  = threadIdx.x;
    const int wave = tid >> 6;
    const int lane = tid & 63;

    float s = 0.0f;
    for (int i = tid; i < B; i += 256) s += row_loss[i];
    s = wave_reduce_sum(s);
    if (lane == 0) wsum[wave] = s;
    __syncthreads();
    if (tid == 0)
        out[0] = (wsum[0] + wsum[1] + wsum[2] + wsum[3]) * (1.0f / (float)B);
}

extern "C" void kernel_launch(void* const* d_in, const int* in_sizes, int n_in,
                              void* d_out, int out_size, void* d_ws, size_t ws_size,
                              hipStream_t stream) {
    const float* anchor    = (const float*)d_in[0];
    const float* positive  = (const float*)d_in[1];
    const float* negatives = (const float*)d_in[2];
    float* out      = (float*)d_out;
    float* row_loss = (float*)d_ws;   // B floats = 16 KB scratch

    infonce_rows<<<B, 256, 0, stream>>>(anchor, positive, negatives, row_loss);
    reduce_mean<<<1, 256, 0, stream>>>(row_loss, out);
}